// Round 17
// baseline (2192.144 us; speedup 1.0000x reference)
//
#include <hip/hip_runtime.h>
#include <hip/hip_bf16.h>
#include <math.h>

#define B 2048
#define NN 30
#define H 256
#define EDIM 256
#define G4 1024  // 4*H
#define PAD 44   // LDS row pitch in shorts: 88B stride -> conflict-free b128 frags

typedef __attribute__((ext_vector_type(8))) short short8;     // 8 bf16 = 4 VGPRs
typedef __attribute__((ext_vector_type(4))) float f32x4;

__device__ __forceinline__ float fsig(float x) {
    return __fdividef(1.f, 1.f + __expf(-x));
}
__device__ __forceinline__ float ftanh(float x) {
    return 1.f - __fdividef(2.f, __expf(2.f * x) + 1.f);
}

// 3-way bf16 split by truncation: a = H + M + L + r, |r| <= 2^-24 |a|
__device__ __forceinline__ void split3(float a, unsigned short& h,
                                       unsigned short& m_, unsigned short& l_)
{
    unsigned ab = __float_as_uint(a);
    h = (unsigned short)(ab >> 16);
    float r1 = a - __uint_as_float(ab & 0xffff0000u);
    unsigned rb = __float_as_uint(r1);
    m_ = (unsigned short)(rb >> 16);
    float r2 = r1 - __uint_as_float(rb & 0xffff0000u);
    l_ = (unsigned short)(__float_as_uint(r2) >> 16);
}

// ---------------------------------------------------------------------------
// Big precompute GEMM via 3-way-split bf16 MFMA (R14-16 validated math).
// R17: LDS row pitch 40 -> 44 shorts; start bank = fr*22 mod 32 covers 16
// distinct banks -> fragment ds_read_b128 at the 2-access/bank floor.
// ---------------------------------------------------------------------------
__global__ __launch_bounds__(256)
void gemm_big(const float* __restrict__ A,
              const unsigned short* __restrict__ Wh, const unsigned short* __restrict__ Wm,
              const unsigned short* __restrict__ Wl,
              const float* __restrict__ b0, const float* __restrict__ b1,
              const float* __restrict__ b2,
              float* __restrict__ C0, float* __restrict__ C1,
              float* __restrict__ C2)
{
    __shared__ __align__(16) unsigned short Ah[128][PAD];
    __shared__ __align__(16) unsigned short Am[128][PAD];
    __shared__ __align__(16) unsigned short Al[128][PAD];
    __shared__ __align__(16) unsigned short Bh[128][PAD];
    __shared__ __align__(16) unsigned short Bm[128][PAD];
    __shared__ __align__(16) unsigned short Bl[128][PAD];

    int tid = threadIdx.x;
    int w = tid >> 6, l = tid & 63;

    int lin = blockIdx.y * 6 + blockIdx.x;
    int v = (lin & 7) * 360 + (lin >> 3);
    int m0 = (v / 6) << 7;
    int nblk = v % 6;
    int part = nblk >> 1;
    int nin = (nblk & 1) << 7;
    const float* bias = part == 0 ? b0 : part == 1 ? b1 : b2;
    float* C          = part == 0 ? C0 : part == 1 ? C1 : C2;
    long woff = (long)part * 65536;

    int srow = tid >> 1;          // 0..127
    int skb  = (tid & 1) << 4;    // 0 or 16
    const float* arow = A + (long)(m0 + srow) * 256 + skb;
    const unsigned short* wph = Wh + woff + (long)(nin + srow) * 256 + skb;
    const unsigned short* wpm = Wm + woff + (long)(nin + srow) * 256 + skb;
    const unsigned short* wpl = Wl + woff + (long)(nin + srow) * 256 + skb;

    int fr = l & 15;
    int fk = (l >> 4) << 3;       // 0,8,16,24

    f32x4 acc[2][8];
    #pragma unroll
    for (int i = 0; i < 2; ++i)
        #pragma unroll
        for (int j = 0; j < 8; ++j)
            acc[i][j] = (f32x4){0.f, 0.f, 0.f, 0.f};

    for (int kt = 0; kt < 8; ++kt) {
        int k0 = kt << 5;
        float4 a4[4];
        #pragma unroll
        for (int i = 0; i < 4; ++i)
            a4[i] = *(const float4*)(arow + k0 + (i << 2));
        short8 wh0 = *(const short8*)(wph + k0);
        short8 wh1 = *(const short8*)(wph + k0 + 8);
        short8 wm0 = *(const short8*)(wpm + k0);
        short8 wm1 = *(const short8*)(wpm + k0 + 8);
        short8 wl0 = *(const short8*)(wpl + k0);
        short8 wl1 = *(const short8*)(wpl + k0 + 8);

        unsigned short th[16], tm[16], tl[16];
        #pragma unroll
        for (int i = 0; i < 4; ++i) {
            float va[4] = {a4[i].x, a4[i].y, a4[i].z, a4[i].w};
            #pragma unroll
            for (int j = 0; j < 4; ++j)
                split3(va[j], th[(i << 2) + j], tm[(i << 2) + j], tl[(i << 2) + j]);
        }

        __syncthreads();
        *(short8*)&Ah[srow][skb]     = *(const short8*)&th[0];
        *(short8*)&Ah[srow][skb + 8] = *(const short8*)&th[8];
        *(short8*)&Am[srow][skb]     = *(const short8*)&tm[0];
        *(short8*)&Am[srow][skb + 8] = *(const short8*)&tm[8];
        *(short8*)&Al[srow][skb]     = *(const short8*)&tl[0];
        *(short8*)&Al[srow][skb + 8] = *(const short8*)&tl[8];
        *(short8*)&Bh[srow][skb]     = wh0;
        *(short8*)&Bh[srow][skb + 8] = wh1;
        *(short8*)&Bm[srow][skb]     = wm0;
        *(short8*)&Bm[srow][skb + 8] = wm1;
        *(short8*)&Bl[srow][skb]     = wl0;
        *(short8*)&Bl[srow][skb + 8] = wl1;
        __syncthreads();

        short8 aH[2], aM[2], aL[2];
        #pragma unroll
        for (int ms = 0; ms < 2; ++ms) {
            int r = (w << 5) + (ms << 4) + fr;
            aH[ms] = *(const short8*)&Ah[r][fk];
            aM[ms] = *(const short8*)&Am[r][fk];
            aL[ms] = *(const short8*)&Al[r][fk];
        }
        #pragma unroll
        for (int ng = 0; ng < 2; ++ng) {
            short8 bH[4], bM[4], bL[4];
            #pragma unroll
            for (int j = 0; j < 4; ++j) {
                int r = (((ng << 2) + j) << 4) + fr;
                bH[j] = *(const short8*)&Bh[r][fk];
                bM[j] = *(const short8*)&Bm[r][fk];
                bL[j] = *(const short8*)&Bl[r][fk];
            }
            #pragma unroll
            for (int ms = 0; ms < 2; ++ms)
                #pragma unroll
                for (int j = 0; j < 4; ++j)
                    acc[ms][(ng << 2) + j] = __builtin_amdgcn_mfma_f32_16x16x32_bf16(
                        aH[ms], bH[j], acc[ms][(ng << 2) + j], 0, 0, 0);
            #pragma unroll
            for (int ms = 0; ms < 2; ++ms)
                #pragma unroll
                for (int j = 0; j < 4; ++j)
                    acc[ms][(ng << 2) + j] = __builtin_amdgcn_mfma_f32_16x16x32_bf16(
                        aH[ms], bM[j], acc[ms][(ng << 2) + j], 0, 0, 0);
            #pragma unroll
            for (int ms = 0; ms < 2; ++ms)
                #pragma unroll
                for (int j = 0; j < 4; ++j)
                    acc[ms][(ng << 2) + j] = __builtin_amdgcn_mfma_f32_16x16x32_bf16(
                        aM[ms], bH[j], acc[ms][(ng << 2) + j], 0, 0, 0);
            #pragma unroll
            for (int ms = 0; ms < 2; ++ms)
                #pragma unroll
                for (int j = 0; j < 4; ++j)
                    acc[ms][(ng << 2) + j] = __builtin_amdgcn_mfma_f32_16x16x32_bf16(
                        aH[ms], bL[j], acc[ms][(ng << 2) + j], 0, 0, 0);
            #pragma unroll
            for (int ms = 0; ms < 2; ++ms)
                #pragma unroll
                for (int j = 0; j < 4; ++j)
                    acc[ms][(ng << 2) + j] = __builtin_amdgcn_mfma_f32_16x16x32_bf16(
                        aM[ms], bM[j], acc[ms][(ng << 2) + j], 0, 0, 0);
            #pragma unroll
            for (int ms = 0; ms < 2; ++ms)
                #pragma unroll
                for (int j = 0; j < 4; ++j)
                    acc[ms][(ng << 2) + j] = __builtin_amdgcn_mfma_f32_16x16x32_bf16(
                        aL[ms], bH[j], acc[ms][(ng << 2) + j], 0, 0, 0);
        }
    }

    #pragma unroll
    for (int ms = 0; ms < 2; ++ms) {
        #pragma unroll
        for (int ns = 0; ns < 8; ++ns) {
            float bv = bias[nin + (ns << 4) + fr];
            #pragma unroll
            for (int r = 0; r < 4; ++r) {
                int m = m0 + (w << 5) + (ms << 4) + ((l >> 4) << 2) + r;
                C[(long)m * 256 + nin + (ns << 4) + fr] = acc[ms][ns][r] + bv;
            }
        }
    }
}

// ---------------------------------------------------------------------------
// LSTM gates via split-bf16 MFMA with LDS staging (R13-16 proven; PAD=44).
// ---------------------------------------------------------------------------
__global__ __launch_bounds__(256)
void gates_mfma(const unsigned short* __restrict__ dhi, const unsigned short* __restrict__ dlo,
                const unsigned short* __restrict__ hhi, const unsigned short* __restrict__ hlo,
                const unsigned short* __restrict__ Whi, const unsigned short* __restrict__ Wlo,
                const float* __restrict__ bsum, const float* __restrict__ cin,
                float* __restrict__ hout, float* __restrict__ cout,
                unsigned short* __restrict__ hohi, unsigned short* __restrict__ holo)
{
    __shared__ __align__(16) unsigned short Ah[128][PAD];
    __shared__ __align__(16) unsigned short Al[128][PAD];
    __shared__ __align__(16) unsigned short Bh[64][PAD];
    __shared__ __align__(16) unsigned short Bl[64][PAD];

    int tid = threadIdx.x;
    int w = tid >> 6, l = tid & 63;
    int lin = blockIdx.x;                    // 256 blocks
    int v = (lin & 7) * 32 + (lin >> 3);     // XCD swizzle
    int m0 = (v >> 4) << 7;
    int u0 = (v & 15) << 4;

    int arow = tid >> 1;
    int akb  = (tid & 1) << 4;
    int brw  = tid >> 2;
    int bkb  = (tid & 3) << 3;
    int wrow = ((brw >> 4) << 8) + u0 + (brw & 15);
    const unsigned short* wph = Whi + (long)wrow * 512 + bkb;
    const unsigned short* wpl = Wlo + (long)wrow * 512 + bkb;

    int fk = (l >> 4) << 3;
    int fr = l & 15;

    f32x4 acc[2][4];
    #pragma unroll
    for (int i = 0; i < 2; ++i)
        #pragma unroll
        for (int j = 0; j < 4; ++j)
            acc[i][j] = (f32x4){0.f, 0.f, 0.f, 0.f};

    for (int kt = 0; kt < 16; ++kt) {
        int k0 = kt << 5;
        const unsigned short* sah; const unsigned short* sal; int kk;
        if (k0 < 256) { sah = dhi; sal = dlo; kk = k0; }
        else          { sah = hhi; sal = hlo; kk = k0 - 256; }
        long abase = (long)(m0 + arow) * 256 + kk + akb;
        short8 a0 = *(const short8*)&sah[abase];
        short8 a1 = *(const short8*)&sah[abase + 8];
        short8 a2 = *(const short8*)&sal[abase];
        short8 a3 = *(const short8*)&sal[abase + 8];
        short8 b0 = *(const short8*)&wph[k0];
        short8 b1 = *(const short8*)&wpl[k0];
        __syncthreads();
        *(short8*)&Ah[arow][akb]     = a0;
        *(short8*)&Ah[arow][akb + 8] = a1;
        *(short8*)&Al[arow][akb]     = a2;
        *(short8*)&Al[arow][akb + 8] = a3;
        *(short8*)&Bh[brw][bkb] = b0;
        *(short8*)&Bl[brw][bkb] = b1;
        __syncthreads();

        short8 aH[2], aL[2], bH[4], bL[4];
        #pragma unroll
        for (int ms = 0; ms < 2; ++ms) {
            int r = (w << 5) + (ms << 4) + fr;
            aH[ms] = *(const short8*)&Ah[r][fk];
            aL[ms] = *(const short8*)&Al[r][fk];
        }
        #pragma unroll
        for (int s = 0; s < 4; ++s) {
            int r = (s << 4) + fr;
            bH[s] = *(const short8*)&Bh[r][fk];
            bL[s] = *(const short8*)&Bl[r][fk];
        }
        #pragma unroll
        for (int ms = 0; ms < 2; ++ms)
            #pragma unroll
            for (int s = 0; s < 4; ++s)
                acc[ms][s] = __builtin_amdgcn_mfma_f32_16x16x32_bf16(aH[ms], bH[s], acc[ms][s], 0, 0, 0);
        #pragma unroll
        for (int ms = 0; ms < 2; ++ms)
            #pragma unroll
            for (int s = 0; s < 4; ++s)
                acc[ms][s] = __builtin_amdgcn_mfma_f32_16x16x32_bf16(aH[ms], bL[s], acc[ms][s], 0, 0, 0);
        #pragma unroll
        for (int ms = 0; ms < 2; ++ms)
            #pragma unroll
            for (int s = 0; s < 4; ++s)
                acc[ms][s] = __builtin_amdgcn_mfma_f32_16x16x32_bf16(aL[ms], bH[s], acc[ms][s], 0, 0, 0);
    }

    int u = u0 + fr;
    float bI = bsum[u], bF = bsum[256 + u], bG = bsum[512 + u], bO = bsum[768 + u];
    #pragma unroll
    for (int ms = 0; ms < 2; ++ms) {
        #pragma unroll
        for (int r = 0; r < 4; ++r) {
            int m = m0 + (w << 5) + (ms << 4) + ((l >> 4) << 2) + r;
            float gi = acc[ms][0][r] + bI;
            float gf = acc[ms][1][r] + bF;
            float gg = acc[ms][2][r] + bG;
            float go = acc[ms][3][r] + bO;
            float cv = cin[(long)m * H + u];
            float cn = fsig(gf) * cv + fsig(gi) * ftanh(gg);
            float hn = fsig(go) * ftanh(cn);
            cout[(long)m * H + u] = cn;
            hout[(long)m * H + u] = hn;
            unsigned hb = __float_as_uint(hn);
            hohi[(long)m * H + u] = (unsigned short)(hb >> 16);
            float lo = hn - __uint_as_float(hb & 0xffff0000u);
            holo[(long)m * H + u] = (unsigned short)(__float_as_uint(lo) >> 16);
        }
    }
}

__global__ void init_state(const unsigned char* __restrict__ vr, const int* __restrict__ start,
                           unsigned char* __restrict__ mask, unsigned char* __restrict__ knn,
                           int* __restrict__ idxs)
{
    int t = blockIdx.x * 256 + threadIdx.x;
    if (t < B * NN) { mask[t] = vr[t] ? 1 : 0; knn[t] = 0; }
    if (t < B) idxs[t] = start[t];
}

// --------------------------- one-time prep kernels -------------------------
__global__ void prep_wsplit(const float* __restrict__ Wih, const float* __restrict__ Whh,
                            const float* __restrict__ bih, const float* __restrict__ bhh,
                            unsigned short* __restrict__ Whi, unsigned short* __restrict__ Wlo,
                            float* __restrict__ bsum)
{
    int n = blockIdx.x, k = threadIdx.x;
    float a = Wih[(long)n * H + k];
    unsigned ab = __float_as_uint(a);
    Whi[(long)n * 512 + k] = (unsigned short)(ab >> 16);
    float alo = a - __uint_as_float(ab & 0xffff0000u);
    Wlo[(long)n * 512 + k] = (unsigned short)(__float_as_uint(alo) >> 16);
    float b = Whh[(long)n * H + k];
    unsigned bb = __float_as_uint(b);
    Whi[(long)n * 512 + 256 + k] = (unsigned short)(bb >> 16);
    float blo = b - __uint_as_float(bb & 0xffff0000u);
    Wlo[(long)n * 512 + 256 + k] = (unsigned short)(__float_as_uint(blo) >> 16);
    if (k == 0) bsum[n] = bih[n] + bhh[n];
}

__global__ void prep_splitW(const float* __restrict__ W0, const float* __restrict__ W1,
                            const float* __restrict__ W2,
                            unsigned short* __restrict__ Wh, unsigned short* __restrict__ Wm,
                            unsigned short* __restrict__ Wl)
{
    int id = blockIdx.x;           // 0..767
    int p = id >> 8, r = id & 255, k = threadIdx.x;
    const float* W = p == 0 ? W0 : p == 1 ? W1 : W2;
    float a = W[(long)r * 256 + k];
    long o = (long)p * 65536 + (long)r * 256 + k;
    split3(a, Wh[o], Wm[o], Wl[o]);
}

__global__ void conv_pair(const float* __restrict__ x,
                          unsigned short* __restrict__ xhi, unsigned short* __restrict__ xlo)
{
    int t = blockIdx.x * 256 + threadIdx.x;
    float a = x[t];
    unsigned ab = __float_as_uint(a);
    xhi[t] = (unsigned short)(ab >> 16);
    float lo = a - __uint_as_float(ab & 0xffff0000u);
    xlo[t] = (unsigned short)(__float_as_uint(lo) >> 16);
}

__global__ void prep_compose1(const float* __restrict__ Wqg, const float* __restrict__ Wm,
                              float* __restrict__ W1cT)
{
    int h = blockIdx.x, k = threadIdx.x;
    float a = 0.f;
    for (int j = 0; j < H; ++j) a = fmaf(Wqg[(long)h * H + j], Wm[(long)j * 288 + k], a);
    W1cT[(long)k * H + h] = a;
}

__global__ void prep_compose2(const float* __restrict__ Wqg, const float* __restrict__ Wm,
                              const float* __restrict__ bm, const float* __restrict__ bqg,
                              float* __restrict__ W2c, float* __restrict__ bc)
{
    int h = blockIdx.x, w = threadIdx.x;
    if (w < 32) {
        float a = 0.f;
        for (int j = 0; j < H; ++j) a = fmaf(Wqg[(long)h * H + j], Wm[(long)j * 288 + 256 + w], a);
        W2c[h * 32 + w] = a;
    } else if (w == 32) {
        float a = 0.f;
        for (int j = 0; j < H; ++j) a = fmaf(Wqg[(long)h * H + j], bm[j], a);
        bc[h] = a + bqg[h];
    }
}

__global__ __launch_bounds__(256)
void prep_qc(const float* __restrict__ cou, const float* __restrict__ W2c,
             const float* __restrict__ bc, float* __restrict__ qc)
{
    __shared__ float sWT[32 * 256];
    __shared__ float sb[256];
    int b = blockIdx.x, h = threadIdx.x;
    for (int i = h; i < 32 * 256; i += 256) {
        int hh = i >> 5, ww = i & 31;
        sWT[ww * 256 + hh] = W2c[i];
    }
    sb[h] = bc[h];
    __syncthreads();
    const float* cr = cou + (long)b * 32;
    float a = sb[h];
    for (int w = 0; w < 32; ++w) a = fmaf(cr[w], sWT[w * 256 + h], a);
    qc[(long)b * H + h] = a;
}

__global__ void prep_composeF(const float* __restrict__ Wqp, const float* __restrict__ Wrg,
                              const float* __restrict__ brg, float* __restrict__ WFc,
                              float* __restrict__ bFc)
{
    int f = blockIdx.x, k = threadIdx.x;
    float a = 0.f;
    for (int j = 0; j < H; ++j) a = fmaf(Wqp[(long)f * H + j], Wrg[(long)j * H + k], a);
    WFc[(long)f * H + k] = a;
    if (k == 0) {
        float s = 0.f;
        for (int j = 0; j < H; ++j) s = fmaf(Wqp[(long)f * H + j], brg[j], s);
        bFc[f] = s;
    }
}

// ---------------------------------------------------------------------------
// mega8 (R15/R16-proven): 512 blocks x 512 thr, 4 b's per block.
// ---------------------------------------------------------------------------
__global__ __launch_bounds__(512)
void mega8(const float* __restrict__ eg, const float* __restrict__ ep,
           const float* __restrict__ F, const float* __restrict__ hout,
           const float* __restrict__ qc, const float* __restrict__ W1cT,
           const float* __restrict__ vg, const float* __restrict__ vp,
           const float* __restrict__ bqp,
           const float* __restrict__ D, const int* __restrict__ kminp,
           unsigned char* __restrict__ mask, unsigned char* __restrict__ knn,
           const float* __restrict__ emb,
           float* __restrict__ out, int step,
           int* __restrict__ idxs,
           unsigned short* __restrict__ dechi, unsigned short* __restrict__ declo)
{
    __shared__ float sHy[4][256];
    __shared__ float sQg[4][256];
    __shared__ float sU[4][32];
    __shared__ float sPar[4][2][256];
    __shared__ unsigned char sFull[4][32];

    int tid = threadIdx.x;
    int wv = tid >> 6, lane = tid & 63;
    int pi = wv >> 1, sub = wv & 1;
    int blk = blockIdx.x;
    int vB = (blk & 7) * 64 + (blk >> 3);   // XCD swizzle over 512 blocks
    int b0 = vB << 2;
    int b = b0 + pi;

    #pragma unroll
    for (int i = 0; i < 2; ++i) {
        int idx2 = tid + (i << 9);
        int bl = idx2 >> 8, hh = idx2 & 255;
        sHy[bl][hh] = hout[(long)(b0 + bl) * H + hh];
    }
    __syncthreads();

    {
        int hh = tid & 255, g = tid >> 8;
        float a0 = 0.f, a1 = 0.f;
        const float* wp = W1cT + hh;
        const float* h0p = sHy[(g << 1)];
        const float* h1p = sHy[(g << 1) + 1];
        #pragma unroll 4
        for (int k = 0; k < 256; ++k) {
            float wval = wp[(long)k * H];
            a0 = fmaf(h0p[k], wval, a0);
            a1 = fmaf(h1p[k], wval, a1);
        }
        sQg[(g << 1)][hh]     = qc[(long)(b0 + (g << 1)) * H + hh] + a0;
        sQg[(g << 1) + 1][hh] = qc[(long)(b0 + (g << 1) + 1) * H + hh] + a1;
    }

    if (sub == 0) {
        bool in = lane < NN;
        int idx = idxs[b];
        int kmin = *kminp;
        unsigned char m = in ? mask[b * NN + lane] : (unsigned char)1;
        float dv = in ? D[((long)b * NN + idx) * NN + lane] : 0.f;
        unsigned long long unm = __ballot(in && !m);
        int cnt = __popcll(unm);
        bool valid = cnt > kmin;
        float bw = (in && !m) ? dv : (in ? 0.f : -1.f);
        int bi = in ? lane : 1000;
        #pragma unroll
        for (int off = 32; off; off >>= 1) {
            float ow = __shfl_down(bw, off, 64);
            int oi = __shfl_down(bi, off, 64);
            if (ow > bw || (ow == bw && oi < bi)) { bw = ow; bi = oi; }
        }
        int far = __shfl(bi, 0, 64);
        unsigned char mnew = (in && lane == idx) ? 1 : m;
        #pragma unroll
        for (int rep = 0; rep < 2; ++rep) {
            bool allm = (__ballot(in && !mnew) == 0ull);
            if (allm && lane == NN - 1) mnew = 0;
        }
        unsigned char kn = in ? knn[b * NN + lane] : 0;
        if (in) {
            sFull[pi][lane] = (mnew | kn) ? 1 : 0;
            mask[b * NN + lane] = mnew;
            knn[b * NN + lane] = (lane == far && valid) ? 1 : 0;
        }
    }
    __syncthreads();

    float4 vg4 = ((const float4*)vg)[lane];
    float4 vp4 = ((const float4*)vp)[lane];

    {
        float4 q4 = ((const float4*)&sQg[pi][0])[lane];
        for (int n = sub; n < NN; n += 2) {
            if (sFull[pi][n]) continue;
            float4 e4 = ((const float4*)(eg + ((long)n * B + b) * H))[lane];
            float s = vg4.x * ftanh(q4.x + e4.x);
            s = fmaf(vg4.y, ftanh(q4.y + e4.y), s);
            s = fmaf(vg4.z, ftanh(q4.z + e4.z), s);
            s = fmaf(vg4.w, ftanh(q4.w + e4.w), s);
            #pragma unroll
            for (int off = 32; off; off >>= 1) s += __shfl_down(s, off, 64);
            if (lane == 0) sU[pi][n] = s;
        }
    }
    __syncthreads();

    float pr;
    {
        bool in = lane < NN;
        bool fm = in ? (sFull[pi][lane] != 0) : true;
        float u = (in && !fm) ? sU[pi][lane] : -INFINITY;
        float mx = u;
        #pragma unroll
        for (int off = 32; off; off >>= 1) mx = fmaxf(mx, __shfl_down(mx, off, 64));
        mx = __shfl(mx, 0, 64);
        float p = (in && !fm) ? __expf(u - mx) : 0.f;
        float sum = p;
        #pragma unroll
        for (int off = 32; off; off >>= 1) sum += __shfl_down(sum, off, 64);
        sum = __shfl(sum, 0, 64);
        pr = p / sum;
    }

    {
        float4 qa = {0.f, 0.f, 0.f, 0.f};
        for (int n = sub; n < NN; n += 2) {
            float pn = __shfl(pr, n, 64);
            if (pn != 0.f) {
                float4 F4 = ((const float4*)(F + ((long)n * B + b) * H))[lane];
                qa.x = fmaf(pn, F4.x, qa.x);
                qa.y = fmaf(pn, F4.y, qa.y);
                qa.z = fmaf(pn, F4.z, qa.z);
                qa.w = fmaf(pn, F4.w, qa.w);
            }
        }
        ((float4*)&sPar[pi][sub][0])[lane] = qa;
    }
    __syncthreads();

    float4 qp4;
    {
        float4 p0 = ((const float4*)&sPar[pi][0][0])[lane];
        float4 p1 = ((const float4*)&sPar[pi][1][0])[lane];
        float4 bq4 = ((const float4*)bqp)[lane];
        qp4 = make_float4(bq4.x + p0.x + p1.x, bq4.y + p0.y + p1.y,
                          bq4.z + p0.z + p1.z, bq4.w + p0.w + p1.w);
    }

    for (int n = sub; n < NN; n += 2) {
        if (sFull[pi][n]) continue;
        float4 e4 = ((const float4*)(ep + ((long)n * B + b) * H))[lane];
        float s = vp4.x * ftanh(qp4.x + e4.x);
        s = fmaf(vp4.y, ftanh(qp4.y + e4.y), s);
        s = fmaf(vp4.z, ftanh(qp4.z + e4.z), s);
        s = fmaf(vp4.w, ftanh(qp4.w + e4.w), s);
        #pragma unroll
        for (int off = 32; off; off >>= 1) s += __shfl_down(s, off, 64);
        if (lane == 0) sU[pi][n] = 10.f * ftanh(s);
    }
    __syncthreads();

    {
        bool in = lane < NN;
        bool fm = in ? (sFull[pi][lane] != 0) : true;
        float lg = (in && !fm) ? sU[pi][lane] : -INFINITY;
        float mx = lg; int bi = in ? lane : 1000;
        #pragma unroll
        for (int off = 32; off; off >>= 1) {
            float om = __shfl_down(mx, off, 64);
            int oi = __shfl_down(bi, off, 64);
            if (om > mx || (om == mx && oi < bi)) { mx = om; bi = oi; }
        }
        mx = __shfl(mx, 0, 64);
        bi = __shfl(bi, 0, 64);
        float pe = (in && !fm) ? __expf(lg - mx) : 0.f;
        float sum = pe;
        #pragma unroll
        for (int off = 32; off; off >>= 1) sum += __shfl_down(sum, off, 64);
        sum = __shfl(sum, 0, 64);
        float lse = mx + __logf(sum);
        if (sub == 0) {
            if (lane == 0) {
                idxs[b] = bi;
                out[(long)B * NN * NN + (long)b * NN + step] = (float)bi;
            }
            if (in)
                out[(long)b * NN * NN + (long)step * NN + lane] =
                    fm ? -1e30f : (lg - lse);
        }
        int sel = bi;
        int hbase = lane + (sub ? 128 : 0);
        #pragma unroll
        for (int j = 0; j < 2; ++j) {
            int hh = hbase + (j << 6);
            float d = emb[((long)sel * B + b) * EDIM + hh];
            unsigned db = __float_as_uint(d);
            dechi[(long)b * H + hh] = (unsigned short)(db >> 16);
            float lo = d - __uint_as_float(db & 0xffff0000u);
            declo[(long)b * H + hh] = (unsigned short)(__float_as_uint(lo) >> 16);
        }
    }
}

__global__ void mask_out(const unsigned char* __restrict__ mask, float* __restrict__ out)
{
    int t = blockIdx.x * 256 + threadIdx.x;
    if (t < B * NN)
        out[(long)B * NN * NN + (long)B * NN + t] = mask[t] ? 1.f : 0.f;
}

// ---------------------------------------------------------------------------
extern "C" void kernel_launch(void* const* d_in, const int* in_sizes, int n_in,
                              void* d_out, int out_size, void* d_ws, size_t ws_size,
                              hipStream_t stream)
{
    const float* decoder_input = (const float*)d_in[0];
    const float* embedded     = (const float*)d_in[1];
    const float* h0           = (const float*)d_in[2];
    const float* c0           = (const float*)d_in[3];
    const float* context      = (const float*)d_in[4];
    const float* embed_cou    = (const float*)d_in[5];
    const float* D            = (const float*)d_in[6];
    const float* W_ih         = (const float*)d_in[7];
    const float* W_hh         = (const float*)d_in[8];
    const float* b_ih         = (const float*)d_in[9];
    const float* b_hh         = (const float*)d_in[10];
    const float* W_merge      = (const float*)d_in[11];
    const float* b_merge      = (const float*)d_in[12];
    const float* Wq_p         = (const float*)d_in[13];
    const float* bq_p         = (const float*)d_in[14];
    const float* Wr_p         = (const float*)d_in[15];
    const float* br_p         = (const float*)d_in[16];
    const float* v_p          = (const float*)d_in[17];
    const float* Wq_g         = (const float*)d_in[18];
    const float* bq_g         = (const float*)d_in[19];
    const float* Wr_g         = (const float*)d_in[20];
    const float* br_g         = (const float*)d_in[21];
    const float* v_g          = (const float*)d_in[22];
    const unsigned char* vreach = (const unsigned char*)d_in[23];
    const int* start_idx      = (const int*)d_in[24];
    const int* kminp          = (const int*)d_in[25];

    float* ws = (float*)d_ws;
    size_t o = 0;
    float* eg     = ws + o; o += (size_t)B * NN * H;   // [NN][B][H]
    float* ep     = ws + o; o += (size_t)B * NN * H;   // [NN][B][H]
    float* Fbuf   = ws + o; o += (size_t)B * NN * H;   // [NN][B][H]
    float* hb0    = ws + o; o += (size_t)B * H;
    float* hb1    = ws + o; o += (size_t)B * H;
    float* cb0    = ws + o; o += (size_t)B * H;
    float* cb1    = ws + o; o += (size_t)B * H;
    float* qc     = ws + o; o += (size_t)B * H;
    float* W1cT   = ws + o; o += (size_t)H * H;
    float* W2c    = ws + o; o += (size_t)H * 32;
    float* bc     = ws + o; o += (size_t)H;
    float* WFc    = ws + o; o += (size_t)H * H;
    float* bFc    = ws + o; o += (size_t)H;
    float* bsum   = ws + o; o += (size_t)G4;
    unsigned short* Whi  = (unsigned short*)(ws + o); o += (size_t)G4 * 512 / 2;
    unsigned short* Wlo  = (unsigned short*)(ws + o); o += (size_t)G4 * 512 / 2;
    unsigned short* Wsh  = (unsigned short*)(ws + o); o += (size_t)3 * 65536 / 2;
    unsigned short* Wsm  = (unsigned short*)(ws + o); o += (size_t)3 * 65536 / 2;
    unsigned short* Wsl  = (unsigned short*)(ws + o); o += (size_t)3 * 65536 / 2;
    unsigned short* dechi = (unsigned short*)(ws + o); o += (size_t)B * H / 2;
    unsigned short* declo = (unsigned short*)(ws + o); o += (size_t)B * H / 2;
    unsigned short* hAhi = (unsigned short*)(ws + o); o += (size_t)B * H / 2;
    unsigned short* hAlo = (unsigned short*)(ws + o); o += (size_t)B * H / 2;
    unsigned short* hBhi = (unsigned short*)(ws + o); o += (size_t)B * H / 2;
    unsigned short* hBlo = (unsigned short*)(ws + o); o += (size_t)B * H / 2;
    unsigned char* maskb = (unsigned char*)(ws + o);
    unsigned char* knnb  = maskb + (size_t)B * NN;
    int* idxs = (int*)(knnb + (size_t)B * NN + 64);

    float* out = (float*)d_out;

    init_state<<<dim3((B * NN + 255) / 256), dim3(256), 0, stream>>>(
        vreach, start_idx, maskb, knnb, idxs);

    prep_wsplit<<<dim3(G4), dim3(256), 0, stream>>>(W_ih, W_hh, b_ih, b_hh,
                                                    Whi, Wlo, bsum);
    conv_pair<<<dim3(B * H / 256), dim3(256), 0, stream>>>(decoder_input, dechi, declo);
    conv_pair<<<dim3(B * H / 256), dim3(256), 0, stream>>>(h0, hAhi, hAlo);
    prep_compose1<<<dim3(H), dim3(256), 0, stream>>>(Wq_g, W_merge, W1cT);
    prep_compose2<<<dim3(H), dim3(64), 0, stream>>>(Wq_g, W_merge, b_merge, bq_g,
                                                    W2c, bc);
    prep_qc<<<dim3(B), dim3(256), 0, stream>>>(embed_cou, W2c, bc, qc);
    prep_composeF<<<dim3(H), dim3(256), 0, stream>>>(Wq_p, Wr_g, br_g, WFc, bFc);
    prep_splitW<<<dim3(3 * 256), dim3(256), 0, stream>>>(Wr_g, Wr_p, WFc,
                                                         Wsh, Wsm, Wsl);

    gemm_big<<<dim3(6, (B * NN) / 128), dim3(256), 0, stream>>>(
        context, Wsh, Wsm, Wsl, br_g, br_p, bFc, eg, ep, Fbuf);

    const float* cin = c0;
    unsigned short* hInHi = hAhi; unsigned short* hInLo = hAlo;
    unsigned short* hOutHi = hBhi; unsigned short* hOutLo = hBlo;

    for (int step = 0; step < NN; ++step) {
        int p = step & 1;
        float* hout = p ? hb1 : hb0;
        float* cout = p ? cb1 : cb0;

        gates_mfma<<<dim3(256), dim3(256), 0, stream>>>(
            dechi, declo, hInHi, hInLo, Whi, Wlo, bsum, cin,
            hout, cout, hOutHi, hOutLo);

        mega8<<<dim3(B / 4), dim3(512), 0, stream>>>(
            eg, ep, Fbuf, hout, qc, W1cT, v_g, v_p, bq_p, D, kminp,
            maskb, knnb, embedded, out, step, idxs, dechi, declo);

        cin = cout;
        unsigned short* th = hInHi; hInHi = hOutHi; hOutHi = th;
        unsigned short* tl = hInLo; hInLo = hOutLo; hOutLo = tl;
    }

    mask_out<<<dim3((B * NN + 255) / 256), dim3(256), 0, stream>>>(maskb, out);
}

// Round 18
// 2172.064 us; speedup vs baseline: 1.0092x; 1.0092x over previous
//
#include <hip/hip_runtime.h>
#include <hip/hip_bf16.h>
#include <math.h>

#define B 2048
#define NN 30
#define H 256
#define EDIM 256
#define G4 1024  // 4*H
#define PAD 40   // 80B pitch: 16B-aligned rows; b128 frags at 2-access/bank floor

typedef __attribute__((ext_vector_type(8))) short short8;     // 8 bf16 = 4 VGPRs
typedef __attribute__((ext_vector_type(4))) float f32x4;

__device__ __forceinline__ float fsig(float x) {
    return __fdividef(1.f, 1.f + __expf(-x));
}
__device__ __forceinline__ float ftanh(float x) {
    return 1.f - __fdividef(2.f, __expf(2.f * x) + 1.f);
}

// 3-way bf16 split by truncation: a = H + M + L + r, |r| <= 2^-24 |a|
__device__ __forceinline__ void split3(float a, unsigned short& h,
                                       unsigned short& m_, unsigned short& l_)
{
    unsigned ab = __float_as_uint(a);
    h = (unsigned short)(ab >> 16);
    float r1 = a - __uint_as_float(ab & 0xffff0000u);
    unsigned rb = __float_as_uint(r1);
    m_ = (unsigned short)(rb >> 16);
    float r2 = r1 - __uint_as_float(rb & 0xffff0000u);
    l_ = (unsigned short)(__float_as_uint(r2) >> 16);
}

// ---------------------------------------------------------------------------
// Big precompute GEMM via 3-way-split bf16 MFMA (R14-16 validated math).
// R18: register-prefetch ladder - loads for kt+1 issued after the LDS-write
// barrier, so L2/HBM latency hides under the 96-MFMA compute block.
// ---------------------------------------------------------------------------
__global__ __launch_bounds__(256)
void gemm_big(const float* __restrict__ A,
              const unsigned short* __restrict__ Wh, const unsigned short* __restrict__ Wm,
              const unsigned short* __restrict__ Wl,
              const float* __restrict__ b0, const float* __restrict__ b1,
              const float* __restrict__ b2,
              float* __restrict__ C0, float* __restrict__ C1,
              float* __restrict__ C2)
{
    __shared__ __align__(16) unsigned short Ah[128][PAD];
    __shared__ __align__(16) unsigned short Am[128][PAD];
    __shared__ __align__(16) unsigned short Al[128][PAD];
    __shared__ __align__(16) unsigned short Bh[128][PAD];
    __shared__ __align__(16) unsigned short Bm[128][PAD];
    __shared__ __align__(16) unsigned short Bl[128][PAD];

    int tid = threadIdx.x;
    int w = tid >> 6, l = tid & 63;

    int lin = blockIdx.y * 6 + blockIdx.x;
    int v = (lin & 7) * 360 + (lin >> 3);
    int m0 = (v / 6) << 7;
    int nblk = v % 6;
    int part = nblk >> 1;
    int nin = (nblk & 1) << 7;
    const float* bias = part == 0 ? b0 : part == 1 ? b1 : b2;
    float* C          = part == 0 ? C0 : part == 1 ? C1 : C2;
    long woff = (long)part * 65536;

    int srow = tid >> 1;          // 0..127
    int skb  = (tid & 1) << 4;    // 0 or 16
    const float* arow = A + (long)(m0 + srow) * 256 + skb;
    const unsigned short* wph = Wh + woff + (long)(nin + srow) * 256 + skb;
    const unsigned short* wpm = Wm + woff + (long)(nin + srow) * 256 + skb;
    const unsigned short* wpl = Wl + woff + (long)(nin + srow) * 256 + skb;

    int fr = l & 15;
    int fk = (l >> 4) << 3;       // 0,8,16,24

    f32x4 acc[2][8];
    #pragma unroll
    for (int i = 0; i < 2; ++i)
        #pragma unroll
        for (int j = 0; j < 8; ++j)
            acc[i][j] = (f32x4){0.f, 0.f, 0.f, 0.f};

    // prologue: load kt=0
    float4 a4[4];
    short8 wh0, wh1, wm0, wm1, wl0, wl1;
    #pragma unroll
    for (int i = 0; i < 4; ++i)
        a4[i] = *(const float4*)(arow + (i << 2));
    wh0 = *(const short8*)(wph);
    wh1 = *(const short8*)(wph + 8);
    wm0 = *(const short8*)(wpm);
    wm1 = *(const short8*)(wpm + 8);
    wl0 = *(const short8*)(wpl);
    wl1 = *(const short8*)(wpl + 8);

    for (int kt = 0; kt < 8; ++kt) {
        unsigned short th[16], tm[16], tl[16];
        #pragma unroll
        for (int i = 0; i < 4; ++i) {
            float va[4] = {a4[i].x, a4[i].y, a4[i].z, a4[i].w};
            #pragma unroll
            for (int j = 0; j < 4; ++j)
                split3(va[j], th[(i << 2) + j], tm[(i << 2) + j], tl[(i << 2) + j]);
        }

        __syncthreads();   // previous iteration's LDS reads done
        *(short8*)&Ah[srow][skb]     = *(const short8*)&th[0];
        *(short8*)&Ah[srow][skb + 8] = *(const short8*)&th[8];
        *(short8*)&Am[srow][skb]     = *(const short8*)&tm[0];
        *(short8*)&Am[srow][skb + 8] = *(const short8*)&tm[8];
        *(short8*)&Al[srow][skb]     = *(const short8*)&tl[0];
        *(short8*)&Al[srow][skb + 8] = *(const short8*)&tl[8];
        *(short8*)&Bh[srow][skb]     = wh0;
        *(short8*)&Bh[srow][skb + 8] = wh1;
        *(short8*)&Bm[srow][skb]     = wm0;
        *(short8*)&Bm[srow][skb + 8] = wm1;
        *(short8*)&Bl[srow][skb]     = wl0;
        *(short8*)&Bl[srow][skb + 8] = wl1;
        __syncthreads();

        // prefetch kt+1 (latency hides under the MFMA block below)
        if (kt + 1 < 8) {
            int k1 = (kt + 1) << 5;
            #pragma unroll
            for (int i = 0; i < 4; ++i)
                a4[i] = *(const float4*)(arow + k1 + (i << 2));
            wh0 = *(const short8*)(wph + k1);
            wh1 = *(const short8*)(wph + k1 + 8);
            wm0 = *(const short8*)(wpm + k1);
            wm1 = *(const short8*)(wpm + k1 + 8);
            wl0 = *(const short8*)(wpl + k1);
            wl1 = *(const short8*)(wpl + k1 + 8);
        }

        short8 aH[2], aM[2], aL[2];
        #pragma unroll
        for (int ms = 0; ms < 2; ++ms) {
            int r = (w << 5) + (ms << 4) + fr;
            aH[ms] = *(const short8*)&Ah[r][fk];
            aM[ms] = *(const short8*)&Am[r][fk];
            aL[ms] = *(const short8*)&Al[r][fk];
        }
        #pragma unroll
        for (int ng = 0; ng < 2; ++ng) {
            short8 bH[4], bM[4], bL[4];
            #pragma unroll
            for (int j = 0; j < 4; ++j) {
                int r = (((ng << 2) + j) << 4) + fr;
                bH[j] = *(const short8*)&Bh[r][fk];
                bM[j] = *(const short8*)&Bm[r][fk];
                bL[j] = *(const short8*)&Bl[r][fk];
            }
            #pragma unroll
            for (int ms = 0; ms < 2; ++ms)
                #pragma unroll
                for (int j = 0; j < 4; ++j)
                    acc[ms][(ng << 2) + j] = __builtin_amdgcn_mfma_f32_16x16x32_bf16(
                        aH[ms], bH[j], acc[ms][(ng << 2) + j], 0, 0, 0);
            #pragma unroll
            for (int ms = 0; ms < 2; ++ms)
                #pragma unroll
                for (int j = 0; j < 4; ++j)
                    acc[ms][(ng << 2) + j] = __builtin_amdgcn_mfma_f32_16x16x32_bf16(
                        aH[ms], bM[j], acc[ms][(ng << 2) + j], 0, 0, 0);
            #pragma unroll
            for (int ms = 0; ms < 2; ++ms)
                #pragma unroll
                for (int j = 0; j < 4; ++j)
                    acc[ms][(ng << 2) + j] = __builtin_amdgcn_mfma_f32_16x16x32_bf16(
                        aM[ms], bH[j], acc[ms][(ng << 2) + j], 0, 0, 0);
            #pragma unroll
            for (int ms = 0; ms < 2; ++ms)
                #pragma unroll
                for (int j = 0; j < 4; ++j)
                    acc[ms][(ng << 2) + j] = __builtin_amdgcn_mfma_f32_16x16x32_bf16(
                        aH[ms], bL[j], acc[ms][(ng << 2) + j], 0, 0, 0);
            #pragma unroll
            for (int ms = 0; ms < 2; ++ms)
                #pragma unroll
                for (int j = 0; j < 4; ++j)
                    acc[ms][(ng << 2) + j] = __builtin_amdgcn_mfma_f32_16x16x32_bf16(
                        aM[ms], bM[j], acc[ms][(ng << 2) + j], 0, 0, 0);
            #pragma unroll
            for (int ms = 0; ms < 2; ++ms)
                #pragma unroll
                for (int j = 0; j < 4; ++j)
                    acc[ms][(ng << 2) + j] = __builtin_amdgcn_mfma_f32_16x16x32_bf16(
                        aL[ms], bH[j], acc[ms][(ng << 2) + j], 0, 0, 0);
        }
    }

    #pragma unroll
    for (int ms = 0; ms < 2; ++ms) {
        #pragma unroll
        for (int ns = 0; ns < 8; ++ns) {
            float bv = bias[nin + (ns << 4) + fr];
            #pragma unroll
            for (int r = 0; r < 4; ++r) {
                int m = m0 + (w << 5) + (ms << 4) + ((l >> 4) << 2) + r;
                C[(long)m * 256 + nin + (ns << 4) + fr] = acc[ms][ns][r] + bv;
            }
        }
    }
}

// ---------------------------------------------------------------------------
// LSTM gates via split-bf16 MFMA with LDS staging (R13-16 proven) +
// R18 register-prefetch ladder.
// ---------------------------------------------------------------------------
__global__ __launch_bounds__(256)
void gates_mfma(const unsigned short* __restrict__ dhi, const unsigned short* __restrict__ dlo,
                const unsigned short* __restrict__ hhi, const unsigned short* __restrict__ hlo,
                const unsigned short* __restrict__ Whi, const unsigned short* __restrict__ Wlo,
                const float* __restrict__ bsum, const float* __restrict__ cin,
                float* __restrict__ hout, float* __restrict__ cout,
                unsigned short* __restrict__ hohi, unsigned short* __restrict__ holo)
{
    __shared__ __align__(16) unsigned short Ah[128][PAD];
    __shared__ __align__(16) unsigned short Al[128][PAD];
    __shared__ __align__(16) unsigned short Bh[64][PAD];
    __shared__ __align__(16) unsigned short Bl[64][PAD];

    int tid = threadIdx.x;
    int w = tid >> 6, l = tid & 63;
    int lin = blockIdx.x;                    // 256 blocks
    int v = (lin & 7) * 32 + (lin >> 3);     // XCD swizzle
    int m0 = (v >> 4) << 7;
    int u0 = (v & 15) << 4;

    int arow = tid >> 1;
    int akb  = (tid & 1) << 4;
    int brw  = tid >> 2;
    int bkb  = (tid & 3) << 3;
    int wrow = ((brw >> 4) << 8) + u0 + (brw & 15);
    const unsigned short* wph = Whi + (long)wrow * 512 + bkb;
    const unsigned short* wpl = Wlo + (long)wrow * 512 + bkb;

    int fk = (l >> 4) << 3;
    int fr = l & 15;

    f32x4 acc[2][4];
    #pragma unroll
    for (int i = 0; i < 2; ++i)
        #pragma unroll
        for (int j = 0; j < 4; ++j)
            acc[i][j] = (f32x4){0.f, 0.f, 0.f, 0.f};

    // prologue: load kt=0
    short8 a0, a1, a2, a3, b0, b1;
    {
        long abase = (long)(m0 + arow) * 256 + akb;
        a0 = *(const short8*)&dhi[abase];
        a1 = *(const short8*)&dhi[abase + 8];
        a2 = *(const short8*)&dlo[abase];
        a3 = *(const short8*)&dlo[abase + 8];
        b0 = *(const short8*)&wph[0];
        b1 = *(const short8*)&wpl[0];
    }

    for (int kt = 0; kt < 16; ++kt) {
        __syncthreads();
        *(short8*)&Ah[arow][akb]     = a0;
        *(short8*)&Ah[arow][akb + 8] = a1;
        *(short8*)&Al[arow][akb]     = a2;
        *(short8*)&Al[arow][akb + 8] = a3;
        *(short8*)&Bh[brw][bkb] = b0;
        *(short8*)&Bl[brw][bkb] = b1;
        __syncthreads();

        // prefetch kt+1
        if (kt + 1 < 16) {
            int k1 = (kt + 1) << 5;
            const unsigned short* sah; const unsigned short* sal; int kk;
            if (k1 < 256) { sah = dhi; sal = dlo; kk = k1; }
            else          { sah = hhi; sal = hlo; kk = k1 - 256; }
            long abase = (long)(m0 + arow) * 256 + kk + akb;
            a0 = *(const short8*)&sah[abase];
            a1 = *(const short8*)&sah[abase + 8];
            a2 = *(const short8*)&sal[abase];
            a3 = *(const short8*)&sal[abase + 8];
            b0 = *(const short8*)&wph[k1];
            b1 = *(const short8*)&wpl[k1];
        }

        short8 aH[2], aL[2], bH[4], bL[4];
        #pragma unroll
        for (int ms = 0; ms < 2; ++ms) {
            int r = (w << 5) + (ms << 4) + fr;
            aH[ms] = *(const short8*)&Ah[r][fk];
            aL[ms] = *(const short8*)&Al[r][fk];
        }
        #pragma unroll
        for (int s = 0; s < 4; ++s) {
            int r = (s << 4) + fr;
            bH[s] = *(const short8*)&Bh[r][fk];
            bL[s] = *(const short8*)&Bl[r][fk];
        }
        #pragma unroll
        for (int ms = 0; ms < 2; ++ms)
            #pragma unroll
            for (int s = 0; s < 4; ++s)
                acc[ms][s] = __builtin_amdgcn_mfma_f32_16x16x32_bf16(aH[ms], bH[s], acc[ms][s], 0, 0, 0);
        #pragma unroll
        for (int ms = 0; ms < 2; ++ms)
            #pragma unroll
            for (int s = 0; s < 4; ++s)
                acc[ms][s] = __builtin_amdgcn_mfma_f32_16x16x32_bf16(aH[ms], bL[s], acc[ms][s], 0, 0, 0);
        #pragma unroll
        for (int ms = 0; ms < 2; ++ms)
            #pragma unroll
            for (int s = 0; s < 4; ++s)
                acc[ms][s] = __builtin_amdgcn_mfma_f32_16x16x32_bf16(aL[ms], bH[s], acc[ms][s], 0, 0, 0);
    }

    int u = u0 + fr;
    float bI = bsum[u], bF = bsum[256 + u], bG = bsum[512 + u], bO = bsum[768 + u];
    #pragma unroll
    for (int ms = 0; ms < 2; ++ms) {
        #pragma unroll
        for (int r = 0; r < 4; ++r) {
            int m = m0 + (w << 5) + (ms << 4) + ((l >> 4) << 2) + r;
            float gi = acc[ms][0][r] + bI;
            float gf = acc[ms][1][r] + bF;
            float gg = acc[ms][2][r] + bG;
            float go = acc[ms][3][r] + bO;
            float cv = cin[(long)m * H + u];
            float cn = fsig(gf) * cv + fsig(gi) * ftanh(gg);
            float hn = fsig(go) * ftanh(cn);
            cout[(long)m * H + u] = cn;
            hout[(long)m * H + u] = hn;
            unsigned hb = __float_as_uint(hn);
            hohi[(long)m * H + u] = (unsigned short)(hb >> 16);
            float lo = hn - __uint_as_float(hb & 0xffff0000u);
            holo[(long)m * H + u] = (unsigned short)(__float_as_uint(lo) >> 16);
        }
    }
}

__global__ void init_state(const unsigned char* __restrict__ vr, const int* __restrict__ start,
                           unsigned char* __restrict__ mask, unsigned char* __restrict__ knn,
                           int* __restrict__ idxs)
{
    int t = blockIdx.x * 256 + threadIdx.x;
    if (t < B * NN) { mask[t] = vr[t] ? 1 : 0; knn[t] = 0; }
    if (t < B) idxs[t] = start[t];
}

// --------------------------- one-time prep kernels -------------------------
__global__ void prep_wsplit(const float* __restrict__ Wih, const float* __restrict__ Whh,
                            const float* __restrict__ bih, const float* __restrict__ bhh,
                            unsigned short* __restrict__ Whi, unsigned short* __restrict__ Wlo,
                            float* __restrict__ bsum)
{
    int n = blockIdx.x, k = threadIdx.x;
    float a = Wih[(long)n * H + k];
    unsigned ab = __float_as_uint(a);
    Whi[(long)n * 512 + k] = (unsigned short)(ab >> 16);
    float alo = a - __uint_as_float(ab & 0xffff0000u);
    Wlo[(long)n * 512 + k] = (unsigned short)(__float_as_uint(alo) >> 16);
    float b = Whh[(long)n * H + k];
    unsigned bb = __float_as_uint(b);
    Whi[(long)n * 512 + 256 + k] = (unsigned short)(bb >> 16);
    float blo = b - __uint_as_float(bb & 0xffff0000u);
    Wlo[(long)n * 512 + 256 + k] = (unsigned short)(__float_as_uint(blo) >> 16);
    if (k == 0) bsum[n] = bih[n] + bhh[n];
}

__global__ void prep_splitW(const float* __restrict__ W0, const float* __restrict__ W1,
                            const float* __restrict__ W2,
                            unsigned short* __restrict__ Wh, unsigned short* __restrict__ Wm,
                            unsigned short* __restrict__ Wl)
{
    int id = blockIdx.x;           // 0..767
    int p = id >> 8, r = id & 255, k = threadIdx.x;
    const float* W = p == 0 ? W0 : p == 1 ? W1 : W2;
    float a = W[(long)r * 256 + k];
    long o = (long)p * 65536 + (long)r * 256 + k;
    split3(a, Wh[o], Wm[o], Wl[o]);
}

__global__ void conv_pair(const float* __restrict__ x,
                          unsigned short* __restrict__ xhi, unsigned short* __restrict__ xlo)
{
    int t = blockIdx.x * 256 + threadIdx.x;
    float a = x[t];
    unsigned ab = __float_as_uint(a);
    xhi[t] = (unsigned short)(ab >> 16);
    float lo = a - __uint_as_float(ab & 0xffff0000u);
    xlo[t] = (unsigned short)(__float_as_uint(lo) >> 16);
}

__global__ void prep_compose1(const float* __restrict__ Wqg, const float* __restrict__ Wm,
                              float* __restrict__ W1cT)
{
    int h = blockIdx.x, k = threadIdx.x;
    float a = 0.f;
    for (int j = 0; j < H; ++j) a = fmaf(Wqg[(long)h * H + j], Wm[(long)j * 288 + k], a);
    W1cT[(long)k * H + h] = a;
}

__global__ void prep_compose2(const float* __restrict__ Wqg, const float* __restrict__ Wm,
                              const float* __restrict__ bm, const float* __restrict__ bqg,
                              float* __restrict__ W2c, float* __restrict__ bc)
{
    int h = blockIdx.x, w = threadIdx.x;
    if (w < 32) {
        float a = 0.f;
        for (int j = 0; j < H; ++j) a = fmaf(Wqg[(long)h * H + j], Wm[(long)j * 288 + 256 + w], a);
        W2c[h * 32 + w] = a;
    } else if (w == 32) {
        float a = 0.f;
        for (int j = 0; j < H; ++j) a = fmaf(Wqg[(long)h * H + j], bm[j], a);
        bc[h] = a + bqg[h];
    }
}

__global__ __launch_bounds__(256)
void prep_qc(const float* __restrict__ cou, const float* __restrict__ W2c,
             const float* __restrict__ bc, float* __restrict__ qc)
{
    __shared__ float sWT[32 * 256];
    __shared__ float sb[256];
    int b = blockIdx.x, h = threadIdx.x;
    for (int i = h; i < 32 * 256; i += 256) {
        int hh = i >> 5, ww = i & 31;
        sWT[ww * 256 + hh] = W2c[i];
    }
    sb[h] = bc[h];
    __syncthreads();
    const float* cr = cou + (long)b * 32;
    float a = sb[h];
    for (int w = 0; w < 32; ++w) a = fmaf(cr[w], sWT[w * 256 + h], a);
    qc[(long)b * H + h] = a;
}

__global__ void prep_composeF(const float* __restrict__ Wqp, const float* __restrict__ Wrg,
                              const float* __restrict__ brg, float* __restrict__ WFc,
                              float* __restrict__ bFc)
{
    int f = blockIdx.x, k = threadIdx.x;
    float a = 0.f;
    for (int j = 0; j < H; ++j) a = fmaf(Wqp[(long)f * H + j], Wrg[(long)j * H + k], a);
    WFc[(long)f * H + k] = a;
    if (k == 0) {
        float s = 0.f;
        for (int j = 0; j < H; ++j) s = fmaf(Wqp[(long)f * H + j], brg[j], s);
        bFc[f] = s;
    }
}

// ---------------------------------------------------------------------------
// mega8 (R15/R16-proven): 512 blocks x 512 thr, 4 b's per block.
// ---------------------------------------------------------------------------
__global__ __launch_bounds__(512)
void mega8(const float* __restrict__ eg, const float* __restrict__ ep,
           const float* __restrict__ F, const float* __restrict__ hout,
           const float* __restrict__ qc, const float* __restrict__ W1cT,
           const float* __restrict__ vg, const float* __restrict__ vp,
           const float* __restrict__ bqp,
           const float* __restrict__ D, const int* __restrict__ kminp,
           unsigned char* __restrict__ mask, unsigned char* __restrict__ knn,
           const float* __restrict__ emb,
           float* __restrict__ out, int step,
           int* __restrict__ idxs,
           unsigned short* __restrict__ dechi, unsigned short* __restrict__ declo)
{
    __shared__ float sHy[4][256];
    __shared__ float sQg[4][256];
    __shared__ float sU[4][32];
    __shared__ float sPar[4][2][256];
    __shared__ unsigned char sFull[4][32];

    int tid = threadIdx.x;
    int wv = tid >> 6, lane = tid & 63;
    int pi = wv >> 1, sub = wv & 1;
    int blk = blockIdx.x;
    int vB = (blk & 7) * 64 + (blk >> 3);   // XCD swizzle over 512 blocks
    int b0 = vB << 2;
    int b = b0 + pi;

    #pragma unroll
    for (int i = 0; i < 2; ++i) {
        int idx2 = tid + (i << 9);
        int bl = idx2 >> 8, hh = idx2 & 255;
        sHy[bl][hh] = hout[(long)(b0 + bl) * H + hh];
    }
    __syncthreads();

    {
        int hh = tid & 255, g = tid >> 8;
        float a0 = 0.f, a1 = 0.f;
        const float* wp = W1cT + hh;
        const float* h0p = sHy[(g << 1)];
        const float* h1p = sHy[(g << 1) + 1];
        #pragma unroll 4
        for (int k = 0; k < 256; ++k) {
            float wval = wp[(long)k * H];
            a0 = fmaf(h0p[k], wval, a0);
            a1 = fmaf(h1p[k], wval, a1);
        }
        sQg[(g << 1)][hh]     = qc[(long)(b0 + (g << 1)) * H + hh] + a0;
        sQg[(g << 1) + 1][hh] = qc[(long)(b0 + (g << 1) + 1) * H + hh] + a1;
    }

    if (sub == 0) {
        bool in = lane < NN;
        int idx = idxs[b];
        int kmin = *kminp;
        unsigned char m = in ? mask[b * NN + lane] : (unsigned char)1;
        float dv = in ? D[((long)b * NN + idx) * NN + lane] : 0.f;
        unsigned long long unm = __ballot(in && !m);
        int cnt = __popcll(unm);
        bool valid = cnt > kmin;
        float bw = (in && !m) ? dv : (in ? 0.f : -1.f);
        int bi = in ? lane : 1000;
        #pragma unroll
        for (int off = 32; off; off >>= 1) {
            float ow = __shfl_down(bw, off, 64);
            int oi = __shfl_down(bi, off, 64);
            if (ow > bw || (ow == bw && oi < bi)) { bw = ow; bi = oi; }
        }
        int far = __shfl(bi, 0, 64);
        unsigned char mnew = (in && lane == idx) ? 1 : m;
        #pragma unroll
        for (int rep = 0; rep < 2; ++rep) {
            bool allm = (__ballot(in && !mnew) == 0ull);
            if (allm && lane == NN - 1) mnew = 0;
        }
        unsigned char kn = in ? knn[b * NN + lane] : 0;
        if (in) {
            sFull[pi][lane] = (mnew | kn) ? 1 : 0;
            mask[b * NN + lane] = mnew;
            knn[b * NN + lane] = (lane == far && valid) ? 1 : 0;
        }
    }
    __syncthreads();

    float4 vg4 = ((const float4*)vg)[lane];
    float4 vp4 = ((const float4*)vp)[lane];

    {
        float4 q4 = ((const float4*)&sQg[pi][0])[lane];
        for (int n = sub; n < NN; n += 2) {
            if (sFull[pi][n]) continue;
            float4 e4 = ((const float4*)(eg + ((long)n * B + b) * H))[lane];
            float s = vg4.x * ftanh(q4.x + e4.x);
            s = fmaf(vg4.y, ftanh(q4.y + e4.y), s);
            s = fmaf(vg4.z, ftanh(q4.z + e4.z), s);
            s = fmaf(vg4.w, ftanh(q4.w + e4.w), s);
            #pragma unroll
            for (int off = 32; off; off >>= 1) s += __shfl_down(s, off, 64);
            if (lane == 0) sU[pi][n] = s;
        }
    }
    __syncthreads();

    float pr;
    {
        bool in = lane < NN;
        bool fm = in ? (sFull[pi][lane] != 0) : true;
        float u = (in && !fm) ? sU[pi][lane] : -INFINITY;
        float mx = u;
        #pragma unroll
        for (int off = 32; off; off >>= 1) mx = fmaxf(mx, __shfl_down(mx, off, 64));
        mx = __shfl(mx, 0, 64);
        float p = (in && !fm) ? __expf(u - mx) : 0.f;
        float sum = p;
        #pragma unroll
        for (int off = 32; off; off >>= 1) sum += __shfl_down(sum, off, 64);
        sum = __shfl(sum, 0, 64);
        pr = p / sum;
    }

    {
        float4 qa = {0.f, 0.f, 0.f, 0.f};
        for (int n = sub; n < NN; n += 2) {
            float pn = __shfl(pr, n, 64);
            if (pn != 0.f) {
                float4 F4 = ((const float4*)(F + ((long)n * B + b) * H))[lane];
                qa.x = fmaf(pn, F4.x, qa.x);
                qa.y = fmaf(pn, F4.y, qa.y);
                qa.z = fmaf(pn, F4.z, qa.z);
                qa.w = fmaf(pn, F4.w, qa.w);
            }
        }
        ((float4*)&sPar[pi][sub][0])[lane] = qa;
    }
    __syncthreads();

    float4 qp4;
    {
        float4 p0 = ((const float4*)&sPar[pi][0][0])[lane];
        float4 p1 = ((const float4*)&sPar[pi][1][0])[lane];
        float4 bq4 = ((const float4*)bqp)[lane];
        qp4 = make_float4(bq4.x + p0.x + p1.x, bq4.y + p0.y + p1.y,
                          bq4.z + p0.z + p1.z, bq4.w + p0.w + p1.w);
    }

    for (int n = sub; n < NN; n += 2) {
        if (sFull[pi][n]) continue;
        float4 e4 = ((const float4*)(ep + ((long)n * B + b) * H))[lane];
        float s = vp4.x * ftanh(qp4.x + e4.x);
        s = fmaf(vp4.y, ftanh(qp4.y + e4.y), s);
        s = fmaf(vp4.z, ftanh(qp4.z + e4.z), s);
        s = fmaf(vp4.w, ftanh(qp4.w + e4.w), s);
        #pragma unroll
        for (int off = 32; off; off >>= 1) s += __shfl_down(s, off, 64);
        if (lane == 0) sU[pi][n] = 10.f * ftanh(s);
    }
    __syncthreads();

    {
        bool in = lane < NN;
        bool fm = in ? (sFull[pi][lane] != 0) : true;
        float lg = (in && !fm) ? sU[pi][lane] : -INFINITY;
        float mx = lg; int bi = in ? lane : 1000;
        #pragma unroll
        for (int off = 32; off; off >>= 1) {
            float om = __shfl_down(mx, off, 64);
            int oi = __shfl_down(bi, off, 64);
            if (om > mx || (om == mx && oi < bi)) { mx = om; bi = oi; }
        }
        mx = __shfl(mx, 0, 64);
        bi = __shfl(bi, 0, 64);
        float pe = (in && !fm) ? __expf(lg - mx) : 0.f;
        float sum = pe;
        #pragma unroll
        for (int off = 32; off; off >>= 1) sum += __shfl_down(sum, off, 64);
        sum = __shfl(sum, 0, 64);
        float lse = mx + __logf(sum);
        if (sub == 0) {
            if (lane == 0) {
                idxs[b] = bi;
                out[(long)B * NN * NN + (long)b * NN + step] = (float)bi;
            }
            if (in)
                out[(long)b * NN * NN + (long)step * NN + lane] =
                    fm ? -1e30f : (lg - lse);
        }
        int sel = bi;
        int hbase = lane + (sub ? 128 : 0);
        #pragma unroll
        for (int j = 0; j < 2; ++j) {
            int hh = hbase + (j << 6);
            float d = emb[((long)sel * B + b) * EDIM + hh];
            unsigned db = __float_as_uint(d);
            dechi[(long)b * H + hh] = (unsigned short)(db >> 16);
            float lo = d - __uint_as_float(db & 0xffff0000u);
            declo[(long)b * H + hh] = (unsigned short)(__float_as_uint(lo) >> 16);
        }
    }
}

__global__ void mask_out(const unsigned char* __restrict__ mask, float* __restrict__ out)
{
    int t = blockIdx.x * 256 + threadIdx.x;
    if (t < B * NN)
        out[(long)B * NN * NN + (long)B * NN + t] = mask[t] ? 1.f : 0.f;
}

// ---------------------------------------------------------------------------
extern "C" void kernel_launch(void* const* d_in, const int* in_sizes, int n_in,
                              void* d_out, int out_size, void* d_ws, size_t ws_size,
                              hipStream_t stream)
{
    const float* decoder_input = (const float*)d_in[0];
    const float* embedded     = (const float*)d_in[1];
    const float* h0           = (const float*)d_in[2];
    const float* c0           = (const float*)d_in[3];
    const float* context      = (const float*)d_in[4];
    const float* embed_cou    = (const float*)d_in[5];
    const float* D            = (const float*)d_in[6];
    const float* W_ih         = (const float*)d_in[7];
    const float* W_hh         = (const float*)d_in[8];
    const float* b_ih         = (const float*)d_in[9];
    const float* b_hh         = (const float*)d_in[10];
    const float* W_merge      = (const float*)d_in[11];
    const float* b_merge      = (const float*)d_in[12];
    const float* Wq_p         = (const float*)d_in[13];
    const float* bq_p         = (const float*)d_in[14];
    const float* Wr_p         = (const float*)d_in[15];
    const float* br_p         = (const float*)d_in[16];
    const float* v_p          = (const float*)d_in[17];
    const float* Wq_g         = (const float*)d_in[18];
    const float* bq_g         = (const float*)d_in[19];
    const float* Wr_g         = (const float*)d_in[20];
    const float* br_g         = (const float*)d_in[21];
    const float* v_g          = (const float*)d_in[22];
    const unsigned char* vreach = (const unsigned char*)d_in[23];
    const int* start_idx      = (const int*)d_in[24];
    const int* kminp          = (const int*)d_in[25];

    float* ws = (float*)d_ws;
    size_t o = 0;
    float* eg     = ws + o; o += (size_t)B * NN * H;   // [NN][B][H]
    float* ep     = ws + o; o += (size_t)B * NN * H;   // [NN][B][H]
    float* Fbuf   = ws + o; o += (size_t)B * NN * H;   // [NN][B][H]
    float* hb0    = ws + o; o += (size_t)B * H;
    float* hb1    = ws + o; o += (size_t)B * H;
    float* cb0    = ws + o; o += (size_t)B * H;
    float* cb1    = ws + o; o += (size_t)B * H;
    float* qc     = ws + o; o += (size_t)B * H;
    float* W1cT   = ws + o; o += (size_t)H * H;
    float* W2c    = ws + o; o += (size_t)H * 32;
    float* bc     = ws + o; o += (size_t)H;
    float* WFc    = ws + o; o += (size_t)H * H;
    float* bFc    = ws + o; o += (size_t)H;
    float* bsum   = ws + o; o += (size_t)G4;
    unsigned short* Whi  = (unsigned short*)(ws + o); o += (size_t)G4 * 512 / 2;
    unsigned short* Wlo  = (unsigned short*)(ws + o); o += (size_t)G4 * 512 / 2;
    unsigned short* Wsh  = (unsigned short*)(ws + o); o += (size_t)3 * 65536 / 2;
    unsigned short* Wsm  = (unsigned short*)(ws + o); o += (size_t)3 * 65536 / 2;
    unsigned short* Wsl  = (unsigned short*)(ws + o); o += (size_t)3 * 65536 / 2;
    unsigned short* dechi = (unsigned short*)(ws + o); o += (size_t)B * H / 2;
    unsigned short* declo = (unsigned short*)(ws + o); o += (size_t)B * H / 2;
    unsigned short* hAhi = (unsigned short*)(ws + o); o += (size_t)B * H / 2;
    unsigned short* hAlo = (unsigned short*)(ws + o); o += (size_t)B * H / 2;
    unsigned short* hBhi = (unsigned short*)(ws + o); o += (size_t)B * H / 2;
    unsigned short* hBlo = (unsigned short*)(ws + o); o += (size_t)B * H / 2;
    unsigned char* maskb = (unsigned char*)(ws + o);
    unsigned char* knnb  = maskb + (size_t)B * NN;
    int* idxs = (int*)(knnb + (size_t)B * NN + 64);

    float* out = (float*)d_out;

    init_state<<<dim3((B * NN + 255) / 256), dim3(256), 0, stream>>>(
        vreach, start_idx, maskb, knnb, idxs);

    prep_wsplit<<<dim3(G4), dim3(256), 0, stream>>>(W_ih, W_hh, b_ih, b_hh,
                                                    Whi, Wlo, bsum);
    conv_pair<<<dim3(B * H / 256), dim3(256), 0, stream>>>(decoder_input, dechi, declo);
    conv_pair<<<dim3(B * H / 256), dim3(256), 0, stream>>>(h0, hAhi, hAlo);
    prep_compose1<<<dim3(H), dim3(256), 0, stream>>>(Wq_g, W_merge, W1cT);
    prep_compose2<<<dim3(H), dim3(64), 0, stream>>>(Wq_g, W_merge, b_merge, bq_g,
                                                    W2c, bc);
    prep_qc<<<dim3(B), dim3(256), 0, stream>>>(embed_cou, W2c, bc, qc);
    prep_composeF<<<dim3(H), dim3(256), 0, stream>>>(Wq_p, Wr_g, br_g, WFc, bFc);
    prep_splitW<<<dim3(3 * 256), dim3(256), 0, stream>>>(Wr_g, Wr_p, WFc,
                                                         Wsh, Wsm, Wsl);

    gemm_big<<<dim3(6, (B * NN) / 128), dim3(256), 0, stream>>>(
        context, Wsh, Wsm, Wsl, br_g, br_p, bFc, eg, ep, Fbuf);

    const float* cin = c0;
    unsigned short* hInHi = hAhi; unsigned short* hInLo = hAlo;
    unsigned short* hOutHi = hBhi; unsigned short* hOutLo = hBlo;

    for (int step = 0; step < NN; ++step) {
        int p = step & 1;
        float* hout = p ? hb1 : hb0;
        float* cout = p ? cb1 : cb0;

        gates_mfma<<<dim3(256), dim3(256), 0, stream>>>(
            dechi, declo, hInHi, hInLo, Whi, Wlo, bsum, cin,
            hout, cout, hOutHi, hOutLo);

        mega8<<<dim3(B / 4), dim3(512), 0, stream>>>(
            eg, ep, Fbuf, hout, qc, W1cT, v_g, v_p, bq_p, D, kminp,
            maskb, knnb, embedded, out, step, idxs, dechi, declo);

        cin = cout;
        unsigned short* th = hInHi; hInHi = hOutHi; hOutHi = th;
        unsigned short* tl = hInLo; hInLo = hOutLo; hOutLo = tl;
    }

    mask_out<<<dim3((B * NN + 255) / 256), dim3(256), 0, stream>>>(maskb, out);
}